// Round 2
// baseline (120.289 us; speedup 1.0000x reference)
//
#include <hip/hip_runtime.h>
#include <hip/hip_bf16.h>
#include <cstdint>
#include <cstddef>

#define PI_F 3.14159265358979323846f
#define TWO_PI_F 6.28318530717958647692f

typedef __bf16 bf16x8 __attribute__((ext_vector_type(8)));
typedef __bf16 bf16x4 __attribute__((ext_vector_type(4)));
typedef float  f32x4  __attribute__((ext_vector_type(4)));

__device__ __forceinline__ __bf16 to_bf16(float f) { return (__bf16)f; }

// ---------------------------------------------------------------------------
// Kernel P: per-(layer,pair) beamsplitter params -> ws table.
// t4[idx] = (Re(e*c), Im(e*c), Re(e*s), Im(e*s)), t2[idx] = (c, s)
// ---------------------------------------------------------------------------
__global__ __launch_bounds__(256) void olk_params(
    const float* __restrict__ theta, const float* __restrict__ phi,
    float4* __restrict__ t4, float2* __restrict__ t2) {
  int idx = blockIdx.x * 256 + threadIdx.x;  // 256*128 = 32768 total
  float t = fmodf(theta[idx], PI_F);
  float p = phi[idx];
  if (t > 0.5f * PI_F) { t = PI_F - t; p += PI_F; }
  p = fmodf(p, TWO_PI_F);
  float c  = cosf(t), s  = sinf(t);
  float cp = cosf(p), sp = sinf(p);
  t4[idx] = make_float4(cp * c, sp * c, cp * s, sp * s);
  t2[idx] = make_float2(c, s);
}

// ---------------------------------------------------------------------------
// Build kernel: V = e_r^T, then V <- V * T_l for l = 255..0.
// One wave per output row r; lane owns 4 consecutive complex columns.
// ---------------------------------------------------------------------------
struct P8 {
  float4 qa[8];
  float4 qb[8];
  float4 cc[8];
};

template<bool TBL>
__device__ __forceinline__ void loadP8(P8& P, int lb, int lane,
    const float4* __restrict__ t4, const float2* __restrict__ t2,
    const float* __restrict__ theta, const float* __restrict__ phi) {
  if (TBL) {
#pragma unroll
    for (int k = 0; k < 8; ++k) {
      int idx = (lb + k) * 128 + 2 * lane;
      P.qa[k] = t4[idx];
      P.qb[k] = t4[idx + 1];
      P.cc[k] = *(const float4*)&t2[idx];
    }
  } else {
#pragma unroll
    for (int k = 0; k < 8; ++k) {
      int idx = (lb + k) * 128 + 2 * lane;
      float2 th = *(const float2*)&theta[idx];
      float2 ph = *(const float2*)&phi[idx];
      float ta = fmodf(th.x, PI_F), pa = ph.x;
      if (ta > 0.5f * PI_F) { ta = PI_F - ta; pa += PI_F; }
      pa = fmodf(pa, TWO_PI_F);
      float tb = fmodf(th.y, PI_F), pb = ph.y;
      if (tb > 0.5f * PI_F) { tb = PI_F - tb; pb += PI_F; }
      pb = fmodf(pb, TWO_PI_F);
      float ca = cosf(ta), sa = sinf(ta), cpa = cosf(pa), spa = sinf(pa);
      float cb = cosf(tb), sb = sinf(tb), cpb = cosf(pb), spb = sinf(pb);
      P.qa[k] = make_float4(cpa * ca, spa * ca, cpa * sa, spa * sa);
      P.qb[k] = make_float4(cpb * cb, spb * cb, cpb * sb, spb * sb);
      P.cc[k] = make_float4(ca, sa, cb, sb);
    }
  }
}

__device__ __forceinline__ void layer_step(bool odd, int lane,
    float4 qa, float4 qb, float4 cc,
    float& vre0, float& vim0, float& vre1, float& vim1,
    float& vre2, float& vim2, float& vre3, float& vim3) {
  if (!odd) {
    float nr0 = qa.x * vre0 - qa.y * vim0 + qa.z * vre1 - qa.w * vim1;
    float ni0 = qa.x * vim0 + qa.y * vre0 + qa.z * vim1 + qa.w * vre1;
    float nr1 = cc.x * vre1 - cc.y * vre0;
    float ni1 = cc.x * vim1 - cc.y * vim0;
    float nr2 = qb.x * vre2 - qb.y * vim2 + qb.z * vre3 - qb.w * vim3;
    float ni2 = qb.x * vim2 + qb.y * vre2 + qb.z * vim3 + qb.w * vre3;
    float nr3 = cc.z * vre3 - cc.w * vre2;
    float ni3 = cc.z * vim3 - cc.w * vim2;
    vre0 = nr0; vim0 = ni0; vre1 = nr1; vim1 = ni1;
    vre2 = nr2; vim2 = ni2; vre3 = nr3; vim3 = ni3;
  } else {
    int nxt = (lane + 1) & 63, prv = (lane + 63) & 63;
    float xre = __shfl(vre0, nxt, 64);
    float xim = __shfl(vim0, nxt, 64);
    float pre = __shfl(vre3, prv, 64);
    float pim = __shfl(vim3, prv, 64);
    float cp  = __shfl(cc.z, prv, 64);
    float sp  = __shfl(cc.w, prv, 64);
    float nr1 = qa.x * vre1 - qa.y * vim1 + qa.z * vre2 - qa.w * vim2;
    float ni1 = qa.x * vim1 + qa.y * vre1 + qa.z * vim2 + qa.w * vre2;
    float nr2 = cc.x * vre2 - cc.y * vre1;
    float ni2 = cc.x * vim2 - cc.y * vim1;
    float nr3 = qb.x * vre3 - qb.y * vim3 + qb.z * xre - qb.w * xim;
    float ni3 = qb.x * vim3 + qb.y * vre3 + qb.z * xim + qb.w * xre;
    float nr0 = cp * vre0 - sp * pre;
    float ni0 = cp * vim0 - sp * pim;
    vre0 = nr0; vim0 = ni0; vre1 = nr1; vim1 = ni1;
    vre2 = nr2; vim2 = ni2; vre3 = nr3; vim3 = ni3;
  }
}

template<bool TBL>
__global__ __launch_bounds__(256) void olk_build(
    const float* __restrict__ theta, const float* __restrict__ phi,
    const float* __restrict__ outph,
    const float4* __restrict__ t4, const float2* __restrict__ t2,
    __bf16* __restrict__ Tb) {
  int lane = threadIdx.x & 63;
  int r = blockIdx.x * 4 + (threadIdx.x >> 6);
  int c0 = lane * 4;
  float vre0 = (c0 + 0 == r) ? 1.f : 0.f, vim0 = 0.f;
  float vre1 = (c0 + 1 == r) ? 1.f : 0.f, vim1 = 0.f;
  float vre2 = (c0 + 2 == r) ? 1.f : 0.f, vim2 = 0.f;
  float vre3 = (c0 + 3 == r) ? 1.f : 0.f, vim3 = 0.f;

  P8 A, B;
  loadP8<TBL>(A, 31 * 8, lane, t4, t2, theta, phi);
  for (int it = 0; it < 16; ++it) {
    int bA = 31 - 2 * it;
    int bB = bA - 1;
    loadP8<TBL>(B, bB * 8, lane, t4, t2, theta, phi);
#pragma unroll
    for (int k = 7; k >= 0; --k)
      layer_step((k & 1) != 0, lane, A.qa[k], A.qb[k], A.cc[k],
                 vre0, vim0, vre1, vim1, vre2, vim2, vre3, vim3);
    if (it < 15)
      loadP8<TBL>(A, (bB - 1) * 8, lane, t4, t2, theta, phi);
#pragma unroll
    for (int k = 7; k >= 0; --k)
      layer_step((k & 1) != 0, lane, B.qa[k], B.qb[k], B.cc[k],
                 vre0, vim0, vre1, vim1, vre2, vim2, vre3, vim3);
  }

  float oph = outph[r];
  float co = cosf(oph), so = sinf(oph);
  bf16x4 o;
  o[0] = to_bf16(co * vre0 - so * vim0);
  o[1] = to_bf16(co * vre1 - so * vim1);
  o[2] = to_bf16(co * vre2 - so * vim2);
  o[3] = to_bf16(co * vre3 - so * vim3);
  *(bf16x4*)(Tb + r * 256 + c0) = o;
}

// ---------------------------------------------------------------------------
// Matmul: out[131072][64] = x[131072][256] @ T[64][256]^T, bf16 MFMA 16x16x32.
// N-split across waves: wave w of each block owns output cols [16w, 16w+16).
// Per-wave B-resident = 8 frags = 32 VGPRs (vs 128 before) -> 4 waves/SIMD.
// Block's 4 waves stream the SAME 8 m-tiles (x loads coalesce in L1/MSHR).
// Grid 1024 x 256: exactly one full-chip resident pass (4 blocks/CU).
// Fragment layout (verified passing last round):
//   A: m = lane&15, k = 4*(lane>>4)+i (+16 for upper half)
//   B: n = lane&15, same k pattern;  D: col = lane&15, row = 4*(lane>>4)+reg
// ---------------------------------------------------------------------------
union FragB { bf16x8 v; uint2 u2[2]; };
union FragA { bf16x8 v; };

__global__ __launch_bounds__(256, 4) void olk_mm(
    const float* __restrict__ x, const __bf16* __restrict__ Tb,
    float* __restrict__ out) {
  int lane = threadIdx.x & 63;
  int w = threadIdx.x >> 6;            // wave id = output col tile 0..3
  int l15 = lane & 15, lg = lane >> 4;

  FragB b[8];
#pragma unroll
  for (int ks = 0; ks < 8; ++ks) {
    int row = w * 16 + l15;            // T row = output col
    int col = ks * 32 + 4 * lg;
    b[ks].u2[0] = *(const uint2*)(Tb + row * 256 + col);
    b[ks].u2[1] = *(const uint2*)(Tb + row * 256 + col + 16);
  }

#pragma unroll 1
  for (int t = 0; t < 8; ++t) {
    int mt = blockIdx.x * 8 + t;       // m-tile 0..8191
    const float* xr = x + (size_t)(mt * 16 + l15) * 256 + 4 * lg;

    f32x4 acc = (f32x4){0.f, 0.f, 0.f, 0.f};

    // 16 independent dwordx4 loads, all in flight together
    float4 lo[8], hi[8];
#pragma unroll
    for (int ks = 0; ks < 8; ++ks) {
      lo[ks] = *(const float4*)(xr + ks * 32);
      hi[ks] = *(const float4*)(xr + ks * 32 + 16);
    }

#pragma unroll
    for (int ks = 0; ks < 8; ++ks) {
      FragA a;
      a.v[0] = to_bf16(lo[ks].x); a.v[1] = to_bf16(lo[ks].y);
      a.v[2] = to_bf16(lo[ks].z); a.v[3] = to_bf16(lo[ks].w);
      a.v[4] = to_bf16(hi[ks].x); a.v[5] = to_bf16(hi[ks].y);
      a.v[6] = to_bf16(hi[ks].z); a.v[7] = to_bf16(hi[ks].w);
      acc = __builtin_amdgcn_mfma_f32_16x16x32_bf16(a.v, b[ks].v, acc, 0, 0, 0);
    }

    float* ob = out + (size_t)(mt * 16) * 64 + w * 16 + l15;
#pragma unroll
    for (int r = 0; r < 4; ++r)
      ob[(4 * lg + r) * 64] = acc[r];
  }
}

// ---------------------------------------------------------------------------
extern "C" void kernel_launch(void* const* d_in, const int* in_sizes, int n_in,
                              void* d_out, int out_size, void* d_ws, size_t ws_size,
                              hipStream_t stream) {
  const float* x     = (const float*)d_in[0];
  const float* theta = (const float*)d_in[1];
  const float* phi   = (const float*)d_in[2];
  const float* outph = (const float*)d_in[3];
  float* out = (float*)d_out;

  char* ws = (char*)d_ws;
  bool tbl = ws_size >= (size_t)(832 * 1024);
  float4* t4 = (float4*)ws;                       // 512 KB
  float2* t2 = (float2*)(ws + 512 * 1024);        // 256 KB
  __bf16* Tb = (__bf16*)(ws + (tbl ? 768 * 1024 : 0));  // 32 KB bf16 T

  if (tbl) {
    olk_params<<<128, 256, 0, stream>>>(theta, phi, t4, t2);
    olk_build<true><<<16, 256, 0, stream>>>(theta, phi, outph, t4, t2, Tb);
  } else {
    olk_build<false><<<16, 256, 0, stream>>>(theta, phi, outph, nullptr, nullptr, Tb);
  }
  olk_mm<<<1024, 256, 0, stream>>>(x, Tb, out);
}

// Round 3
// 84.630 us; speedup vs baseline: 1.4213x; 1.4213x over previous
//
#include <hip/hip_runtime.h>
#include <hip/hip_bf16.h>
#include <cstdint>
#include <cstddef>

#define PI_F 3.14159265358979323846f
#define TWO_PI_F 6.28318530717958647692f

typedef __bf16 bf16x8 __attribute__((ext_vector_type(8)));
typedef __bf16 bf16x4 __attribute__((ext_vector_type(4)));
typedef float  f32x4  __attribute__((ext_vector_type(4)));

__device__ __forceinline__ __bf16 to_bf16(float f) { return (__bf16)f; }

// global -> LDS async copy, 16B per lane; LDS dest is wave-uniform base + lane*16
#define GLD_LDS16(gsrc, ldst)                                            \
  __builtin_amdgcn_global_load_lds(                                      \
      (const __attribute__((address_space(1))) void*)(gsrc),             \
      (__attribute__((address_space(3))) void*)(ldst), 16, 0, 0)

// ---------------------------------------------------------------------------
// Kernel P: per-(layer,pair) beamsplitter params -> ws table.
// ---------------------------------------------------------------------------
__global__ __launch_bounds__(256) void olk_params(
    const float* __restrict__ theta, const float* __restrict__ phi,
    float4* __restrict__ t4, float2* __restrict__ t2) {
  int idx = blockIdx.x * 256 + threadIdx.x;  // 256*128 = 32768 total
  float t = fmodf(theta[idx], PI_F);
  float p = phi[idx];
  if (t > 0.5f * PI_F) { t = PI_F - t; p += PI_F; }
  p = fmodf(p, TWO_PI_F);
  float c  = cosf(t), s  = sinf(t);
  float cp = cosf(p), sp = sinf(p);
  t4[idx] = make_float4(cp * c, sp * c, cp * s, sp * s);
  t2[idx] = make_float2(c, s);
}

// ---------------------------------------------------------------------------
// Build kernel: V = e_r^T, then V <- V * T_l for l = 255..0 (unchanged).
// ---------------------------------------------------------------------------
struct P8 {
  float4 qa[8];
  float4 qb[8];
  float4 cc[8];
};

template<bool TBL>
__device__ __forceinline__ void loadP8(P8& P, int lb, int lane,
    const float4* __restrict__ t4, const float2* __restrict__ t2,
    const float* __restrict__ theta, const float* __restrict__ phi) {
  if (TBL) {
#pragma unroll
    for (int k = 0; k < 8; ++k) {
      int idx = (lb + k) * 128 + 2 * lane;
      P.qa[k] = t4[idx];
      P.qb[k] = t4[idx + 1];
      P.cc[k] = *(const float4*)&t2[idx];
    }
  } else {
#pragma unroll
    for (int k = 0; k < 8; ++k) {
      int idx = (lb + k) * 128 + 2 * lane;
      float2 th = *(const float2*)&theta[idx];
      float2 ph = *(const float2*)&phi[idx];
      float ta = fmodf(th.x, PI_F), pa = ph.x;
      if (ta > 0.5f * PI_F) { ta = PI_F - ta; pa += PI_F; }
      pa = fmodf(pa, TWO_PI_F);
      float tb = fmodf(th.y, PI_F), pb = ph.y;
      if (tb > 0.5f * PI_F) { tb = PI_F - tb; pb += PI_F; }
      pb = fmodf(pb, TWO_PI_F);
      float ca = cosf(ta), sa = sinf(ta), cpa = cosf(pa), spa = sinf(pa);
      float cb = cosf(tb), sb = sinf(tb), cpb = cosf(pb), spb = sinf(pb);
      P.qa[k] = make_float4(cpa * ca, spa * ca, cpa * sa, spa * sa);
      P.qb[k] = make_float4(cpb * cb, spb * cb, cpb * sb, spb * sb);
      P.cc[k] = make_float4(ca, sa, cb, sb);
    }
  }
}

__device__ __forceinline__ void layer_step(bool odd, int lane,
    float4 qa, float4 qb, float4 cc,
    float& vre0, float& vim0, float& vre1, float& vim1,
    float& vre2, float& vim2, float& vre3, float& vim3) {
  if (!odd) {
    float nr0 = qa.x * vre0 - qa.y * vim0 + qa.z * vre1 - qa.w * vim1;
    float ni0 = qa.x * vim0 + qa.y * vre0 + qa.z * vim1 + qa.w * vre1;
    float nr1 = cc.x * vre1 - cc.y * vre0;
    float ni1 = cc.x * vim1 - cc.y * vim0;
    float nr2 = qb.x * vre2 - qb.y * vim2 + qb.z * vre3 - qb.w * vim3;
    float ni2 = qb.x * vim2 + qb.y * vre2 + qb.z * vim3 + qb.w * vre3;
    float nr3 = cc.z * vre3 - cc.w * vre2;
    float ni3 = cc.z * vim3 - cc.w * vim2;
    vre0 = nr0; vim0 = ni0; vre1 = nr1; vim1 = ni1;
    vre2 = nr2; vim2 = ni2; vre3 = nr3; vim3 = ni3;
  } else {
    int nxt = (lane + 1) & 63, prv = (lane + 63) & 63;
    float xre = __shfl(vre0, nxt, 64);
    float xim = __shfl(vim0, nxt, 64);
    float pre = __shfl(vre3, prv, 64);
    float pim = __shfl(vim3, prv, 64);
    float cp  = __shfl(cc.z, prv, 64);
    float sp  = __shfl(cc.w, prv, 64);
    float nr1 = qa.x * vre1 - qa.y * vim1 + qa.z * vre2 - qa.w * vim2;
    float ni1 = qa.x * vim1 + qa.y * vre1 + qa.z * vim2 + qa.w * vre2;
    float nr2 = cc.x * vre2 - cc.y * vre1;
    float ni2 = cc.x * vim2 - cc.y * vim1;
    float nr3 = qb.x * vre3 - qb.y * vim3 + qb.z * xre - qb.w * xim;
    float ni3 = qb.x * vim3 + qb.y * vre3 + qb.z * xim + qb.w * xre;
    float nr0 = cp * vre0 - sp * pre;
    float ni0 = cp * vim0 - sp * pim;
    vre0 = nr0; vim0 = ni0; vre1 = nr1; vim1 = ni1;
    vre2 = nr2; vim2 = ni2; vre3 = nr3; vim3 = ni3;
  }
}

template<bool TBL>
__global__ __launch_bounds__(256) void olk_build(
    const float* __restrict__ theta, const float* __restrict__ phi,
    const float* __restrict__ outph,
    const float4* __restrict__ t4, const float2* __restrict__ t2,
    __bf16* __restrict__ Tb) {
  int lane = threadIdx.x & 63;
  int r = blockIdx.x * 4 + (threadIdx.x >> 6);
  int c0 = lane * 4;
  float vre0 = (c0 + 0 == r) ? 1.f : 0.f, vim0 = 0.f;
  float vre1 = (c0 + 1 == r) ? 1.f : 0.f, vim1 = 0.f;
  float vre2 = (c0 + 2 == r) ? 1.f : 0.f, vim2 = 0.f;
  float vre3 = (c0 + 3 == r) ? 1.f : 0.f, vim3 = 0.f;

  P8 A, B;
  loadP8<TBL>(A, 31 * 8, lane, t4, t2, theta, phi);
  for (int it = 0; it < 16; ++it) {
    int bA = 31 - 2 * it;
    int bB = bA - 1;
    loadP8<TBL>(B, bB * 8, lane, t4, t2, theta, phi);
#pragma unroll
    for (int k = 7; k >= 0; --k)
      layer_step((k & 1) != 0, lane, A.qa[k], A.qb[k], A.cc[k],
                 vre0, vim0, vre1, vim1, vre2, vim2, vre3, vim3);
    if (it < 15)
      loadP8<TBL>(A, (bB - 1) * 8, lane, t4, t2, theta, phi);
#pragma unroll
    for (int k = 7; k >= 0; --k)
      layer_step((k & 1) != 0, lane, B.qa[k], B.qb[k], B.cc[k],
                 vre0, vim0, vre1, vim1, vre2, vim2, vre3, vim3);
  }

  float oph = outph[r];
  float co = cosf(oph), so = sinf(oph);
  bf16x4 o;
  o[0] = to_bf16(co * vre0 - so * vim0);
  o[1] = to_bf16(co * vre1 - so * vim1);
  o[2] = to_bf16(co * vre2 - so * vim2);
  o[3] = to_bf16(co * vre3 - so * vim3);
  *(bf16x4*)(Tb + r * 256 + c0) = o;
}

// ---------------------------------------------------------------------------
// Matmul: out[131072][64] = x[131072][256] @ T[64][256]^T, bf16 MFMA 16x16x32.
// x staged ONCE per 16-row tile into LDS via global_load_lds (dbuf, counted
// vmcnt); 4 waves share the tile from LDS (n-split, 16 cols each).
// LDS layout: row-major 16B chunks with physchunk = chunk ^ (row&7):
//   - stage instr j of wave w covers row w*4+j: linear LDS dest (HW lane*16),
//     per-lane GLOBAL src chunk = lane ^ (row&7)  (rule #21: swizzle the src)
//   - ds_read_b128 at (row=l15, chunk=8ks+lg(+4)) ^ (l15&7): 8 lanes per
//     bank-group, balanced -> conflict-free b128.
// ---------------------------------------------------------------------------
union FragB { bf16x8 v; uint2 u2[2]; };
union FragA { bf16x8 v; };

__global__ __launch_bounds__(256, 5) void olk_mm(
    const float* __restrict__ x, const __bf16* __restrict__ Tb,
    float* __restrict__ out) {
  __shared__ float4 sbuf[2][1024];     // 2 x 16KB: [row][physchunk], 64 chunks/row
  int tid = threadIdx.x;
  int lane = tid & 63;
  int w = tid >> 6;                    // wave id = output col tile 0..3
  int l15 = lane & 15, lg = lane >> 4;

  // B frags: wave w owns T rows [16w,16w+16) (= output cols)
  FragB b[8];
#pragma unroll
  for (int ks = 0; ks < 8; ++ks) {
    int row = w * 16 + l15;
    int col = ks * 32 + 4 * lg;
    b[ks].u2[0] = *(const uint2*)(Tb + row * 256 + col);
    b[ks].u2[1] = *(const uint2*)(Tb + row * 256 + col + 16);
  }
  // Drain B loads NOW so the compiler never re-waits them inside the loop
  // (an in-loop conservative vmcnt(0) would kill the prefetch pipeline).
  asm volatile("s_waitcnt vmcnt(0)" ::: "memory");

  int tile0 = blockIdx.x * 4;

  // stage tile mt into sbuf[bf]: 4 global_load_lds per thread, one row each
  auto stage = [&](int bf, int mt) {
#pragma unroll
    for (int j = 0; j < 4; ++j) {
      int row = w * 4 + j;                       // wave-uniform
      int c = lane ^ (row & 7);                  // per-lane global chunk
      const float* src = x + ((size_t)(mt * 16 + row) << 8) + c * 4;
      GLD_LDS16(src, &sbuf[bf][row * 64]);       // lane i -> physchunk i
    }
  };

  stage(0, tile0);
#pragma unroll 1
  for (int t = 0; t < 4; ++t) {
    int cur = t & 1;
    if (t < 3) {
      stage(cur ^ 1, tile0 + t + 1);
      // oldest 8 = [4 out-stores of t-1] + [4 loads of tile t] -> tile t landed
      asm volatile("s_waitcnt vmcnt(4)" ::: "memory");
    } else {
      asm volatile("s_waitcnt vmcnt(0)" ::: "memory");
    }
    __builtin_amdgcn_s_barrier();      // all waves' stage of tile t visible

    const float4* A = sbuf[cur];
    int mt = tile0 + t;
    f32x4 acc = (f32x4){0.f, 0.f, 0.f, 0.f};
#pragma unroll
    for (int ks = 0; ks < 8; ++ks) {
      int q0 = 8 * ks + lg;
      int q1 = q0 + 4;
      int sw = l15 & 7;
      float4 lo = A[l15 * 64 + (q0 ^ sw)];
      float4 hi = A[l15 * 64 + (q1 ^ sw)];
      FragA a;
      a.v[0] = to_bf16(lo.x); a.v[1] = to_bf16(lo.y);
      a.v[2] = to_bf16(lo.z); a.v[3] = to_bf16(lo.w);
      a.v[4] = to_bf16(hi.x); a.v[5] = to_bf16(hi.y);
      a.v[6] = to_bf16(hi.z); a.v[7] = to_bf16(hi.w);
      acc = __builtin_amdgcn_mfma_f32_16x16x32_bf16(a.v, b[ks].v, acc, 0, 0, 0);
    }

    float* ob = out + ((size_t)mt * 16) * 64 + w * 16 + l15;
#pragma unroll
    for (int r = 0; r < 4; ++r)
      ob[(4 * lg + r) * 64] = acc[r];

    __builtin_amdgcn_s_barrier();      // everyone done reading sbuf[cur]
  }
}

// ---------------------------------------------------------------------------
extern "C" void kernel_launch(void* const* d_in, const int* in_sizes, int n_in,
                              void* d_out, int out_size, void* d_ws, size_t ws_size,
                              hipStream_t stream) {
  const float* x     = (const float*)d_in[0];
  const float* theta = (const float*)d_in[1];
  const float* phi   = (const float*)d_in[2];
  const float* outph = (const float*)d_in[3];
  float* out = (float*)d_out;

  char* ws = (char*)d_ws;
  bool tbl = ws_size >= (size_t)(832 * 1024);
  float4* t4 = (float4*)ws;                       // 512 KB
  float2* t2 = (float2*)(ws + 512 * 1024);        // 256 KB
  __bf16* Tb = (__bf16*)(ws + (tbl ? 768 * 1024 : 0));  // 32 KB bf16 T

  if (tbl) {
    olk_params<<<128, 256, 0, stream>>>(theta, phi, t4, t2);
    olk_build<true><<<16, 256, 0, stream>>>(theta, phi, outph, t4, t2, Tb);
  } else {
    olk_build<false><<<16, 256, 0, stream>>>(theta, phi, outph, nullptr, nullptr, Tb);
  }
  olk_mm<<<2048, 256, 0, stream>>>(x, Tb, out);
}

// Round 4
// 83.276 us; speedup vs baseline: 1.4445x; 1.0163x over previous
//
#include <hip/hip_runtime.h>
#include <hip/hip_bf16.h>
#include <cstdint>
#include <cstddef>

#define PI_F 3.14159265358979323846f
#define TWO_PI_F 6.28318530717958647692f

typedef __bf16 bf16x8 __attribute__((ext_vector_type(8)));
typedef __bf16 bf16x4 __attribute__((ext_vector_type(4)));
typedef float  f32x4  __attribute__((ext_vector_type(4)));

__device__ __forceinline__ __bf16 to_bf16(float f) { return (__bf16)f; }

// global -> LDS async copy, 16B per lane; LDS dest is wave-uniform base + lane*16
#define GLD_LDS16(gsrc, ldst)                                            \
  __builtin_amdgcn_global_load_lds(                                      \
      (const __attribute__((address_space(1))) void*)(gsrc),             \
      (__attribute__((address_space(3))) void*)(ldst), 16, 0, 0)

// ---------------------------------------------------------------------------
// Kernel P: per-(layer,pair) beamsplitter params -> ws table.
// ---------------------------------------------------------------------------
__global__ __launch_bounds__(256) void olk_params(
    const float* __restrict__ theta, const float* __restrict__ phi,
    float4* __restrict__ t4, float2* __restrict__ t2) {
  int idx = blockIdx.x * 256 + threadIdx.x;  // 256*128 = 32768 total
  float t = fmodf(theta[idx], PI_F);
  float p = phi[idx];
  if (t > 0.5f * PI_F) { t = PI_F - t; p += PI_F; }
  p = fmodf(p, TWO_PI_F);
  float c  = cosf(t), s  = sinf(t);
  float cp = cosf(p), sp = sinf(p);
  t4[idx] = make_float4(cp * c, sp * c, cp * s, sp * s);
  t2[idx] = make_float2(c, s);
}

// ---------------------------------------------------------------------------
// Build kernel: V = e_r^T, then V <- V * T_l for l = 255..0.
// Output is written in MFMA *fragment order* (see olk_mm).
// ---------------------------------------------------------------------------
struct P8 {
  float4 qa[8];
  float4 qb[8];
  float4 cc[8];
};

template<bool TBL>
__device__ __forceinline__ void loadP8(P8& P, int lb, int lane,
    const float4* __restrict__ t4, const float2* __restrict__ t2,
    const float* __restrict__ theta, const float* __restrict__ phi) {
  if (TBL) {
#pragma unroll
    for (int k = 0; k < 8; ++k) {
      int idx = (lb + k) * 128 + 2 * lane;
      P.qa[k] = t4[idx];
      P.qb[k] = t4[idx + 1];
      P.cc[k] = *(const float4*)&t2[idx];
    }
  } else {
#pragma unroll
    for (int k = 0; k < 8; ++k) {
      int idx = (lb + k) * 128 + 2 * lane;
      float2 th = *(const float2*)&theta[idx];
      float2 ph = *(const float2*)&phi[idx];
      float ta = fmodf(th.x, PI_F), pa = ph.x;
      if (ta > 0.5f * PI_F) { ta = PI_F - ta; pa += PI_F; }
      pa = fmodf(pa, TWO_PI_F);
      float tb = fmodf(th.y, PI_F), pb = ph.y;
      if (tb > 0.5f * PI_F) { tb = PI_F - tb; pb += PI_F; }
      pb = fmodf(pb, TWO_PI_F);
      float ca = cosf(ta), sa = sinf(ta), cpa = cosf(pa), spa = sinf(pa);
      float cb = cosf(tb), sb = sinf(tb), cpb = cosf(pb), spb = sinf(pb);
      P.qa[k] = make_float4(cpa * ca, spa * ca, cpa * sa, spa * sa);
      P.qb[k] = make_float4(cpb * cb, spb * cb, cpb * sb, spb * sb);
      P.cc[k] = make_float4(ca, sa, cb, sb);
    }
  }
}

__device__ __forceinline__ void layer_step(bool odd, int lane,
    float4 qa, float4 qb, float4 cc,
    float& vre0, float& vim0, float& vre1, float& vim1,
    float& vre2, float& vim2, float& vre3, float& vim3) {
  if (!odd) {
    float nr0 = qa.x * vre0 - qa.y * vim0 + qa.z * vre1 - qa.w * vim1;
    float ni0 = qa.x * vim0 + qa.y * vre0 + qa.z * vim1 + qa.w * vre1;
    float nr1 = cc.x * vre1 - cc.y * vre0;
    float ni1 = cc.x * vim1 - cc.y * vim0;
    float nr2 = qb.x * vre2 - qb.y * vim2 + qb.z * vre3 - qb.w * vim3;
    float ni2 = qb.x * vim2 + qb.y * vre2 + qb.z * vim3 + qb.w * vre3;
    float nr3 = cc.z * vre3 - cc.w * vre2;
    float ni3 = cc.z * vim3 - cc.w * vim2;
    vre0 = nr0; vim0 = ni0; vre1 = nr1; vim1 = ni1;
    vre2 = nr2; vim2 = ni2; vre3 = nr3; vim3 = ni3;
  } else {
    int nxt = (lane + 1) & 63, prv = (lane + 63) & 63;
    float xre = __shfl(vre0, nxt, 64);
    float xim = __shfl(vim0, nxt, 64);
    float pre = __shfl(vre3, prv, 64);
    float pim = __shfl(vim3, prv, 64);
    float cp  = __shfl(cc.z, prv, 64);
    float sp  = __shfl(cc.w, prv, 64);
    float nr1 = qa.x * vre1 - qa.y * vim1 + qa.z * vre2 - qa.w * vim2;
    float ni1 = qa.x * vim1 + qa.y * vre1 + qa.z * vim2 + qa.w * vre2;
    float nr2 = cc.x * vre2 - cc.y * vre1;
    float ni2 = cc.x * vim2 - cc.y * vim1;
    float nr3 = qb.x * vre3 - qb.y * vim3 + qb.z * xre - qb.w * xim;
    float ni3 = qb.x * vim3 + qb.y * vre3 + qb.z * xim + qb.w * xre;
    float nr0 = cp * vre0 - sp * pre;
    float ni0 = cp * vim0 - sp * pim;
    vre0 = nr0; vim0 = ni0; vre1 = nr1; vim1 = ni1;
    vre2 = nr2; vim2 = ni2; vre3 = nr3; vim3 = ni3;
  }
}

template<bool TBL>
__global__ __launch_bounds__(256) void olk_build(
    const float* __restrict__ theta, const float* __restrict__ phi,
    const float* __restrict__ outph,
    const float4* __restrict__ t4, const float2* __restrict__ t2,
    __bf16* __restrict__ Tb2) {
  int lane = threadIdx.x & 63;
  int r = blockIdx.x * 4 + (threadIdx.x >> 6);
  int c0 = lane * 4;
  float vre0 = (c0 + 0 == r) ? 1.f : 0.f, vim0 = 0.f;
  float vre1 = (c0 + 1 == r) ? 1.f : 0.f, vim1 = 0.f;
  float vre2 = (c0 + 2 == r) ? 1.f : 0.f, vim2 = 0.f;
  float vre3 = (c0 + 3 == r) ? 1.f : 0.f, vim3 = 0.f;

  P8 A, B;
  loadP8<TBL>(A, 31 * 8, lane, t4, t2, theta, phi);
  for (int it = 0; it < 16; ++it) {
    int bA = 31 - 2 * it;
    int bB = bA - 1;
    loadP8<TBL>(B, bB * 8, lane, t4, t2, theta, phi);
#pragma unroll
    for (int k = 7; k >= 0; --k)
      layer_step((k & 1) != 0, lane, A.qa[k], A.qb[k], A.cc[k],
                 vre0, vim0, vre1, vim1, vre2, vim2, vre3, vim3);
    if (it < 15)
      loadP8<TBL>(A, (bB - 1) * 8, lane, t4, t2, theta, phi);
#pragma unroll
    for (int k = 7; k >= 0; --k)
      layer_step((k & 1) != 0, lane, B.qa[k], B.qb[k], B.cc[k],
                 vre0, vim0, vre1, vim1, vre2, vim2, vre3, vim3);
  }

  float oph = outph[r];
  float co = cosf(oph), so = sinf(oph);
  bf16x4 o;
  o[0] = to_bf16(co * vre0 - so * vim0);
  o[1] = to_bf16(co * vre1 - so * vim1);
  o[2] = to_bf16(co * vre2 - so * vim2);
  o[3] = to_bf16(co * vre3 - so * vim3);

  // Fragment-ordered store: within row r, k-block ks keeps 32 cols laid out as
  // [lg=0: {c..c+3, c+16..c+19}, lg=1: ...] so an MFMA B-frag (8 bf16) is a
  // contiguous 16B run at r*256 + ks*32 + lg*8.
  int ks = lane >> 3, sub = lane & 7;
  int pos = ks * 32 + (sub & 3) * 8 + (sub >> 2) * 4;  // this lane's 4 cols
  *(bf16x4*)(Tb2 + r * 256 + pos) = o;
}

// ---------------------------------------------------------------------------
// Matmul: out[131072][64] = x[131072][256] @ T[64][256]^T, bf16 MFMA 16x16x32.
// R2's extraction structure (independent waves, 16 float4 x-loads in flight,
// no in-loop barriers) + zero redundancy: each wave computes ALL 64 output
// cols for its own m-tiles; B lives in LDS (32KB), staged once via
// global_load_lds from the fragment-ordered Tb2 (per-lane global src gather,
// linear LDS dest). Every B read in the loop is uniform_base + lane*16:
// conflict-free, no address math. Grid 1024x256 = 4 blocks/CU, all resident.
// ---------------------------------------------------------------------------
union FragA { bf16x8 v; };

__global__ __launch_bounds__(256, 4) void olk_mm(
    const float* __restrict__ x, const __bf16* __restrict__ Tb2,
    float* __restrict__ out) {
  __shared__ __bf16 Bl[32 * 512];   // 32 frag-sets x 64 lanes x 8 bf16 = 32KB
  int tid = threadIdx.x, lane = tid & 63, w = tid >> 6;
  int l15 = lane & 15, lg = lane >> 4;

  // Stage B fragments: frag-set idx = ks*4+nt; this wave stages idx = w*8+j.
  // Lane's global src = its own (l15,lg) fragment of that set (16B contiguous
  // in Tb2 by construction); LDS dest = idx*1024B + lane*16B (HW-linear).
#pragma unroll
  for (int j = 0; j < 8; ++j) {
    int idx = w * 8 + j;
    int ks = idx >> 2, nt = idx & 3;
    const __bf16* src = Tb2 + (nt * 16 + l15) * 256 + ks * 32 + lg * 8;
    GLD_LDS16(src, &Bl[idx * 512]);
  }
  __syncthreads();   // one-time: drains the B stage, then waves run free

#pragma unroll 1
  for (int t = 0; t < 2; ++t) {
    int mt = (blockIdx.x * 4 + w) * 2 + t;          // m-tile 0..8191
    const float* xr = x + ((size_t)(mt * 16 + l15) << 8) + 4 * lg;

    // 16 independent dwordx4 loads, all issued before first use (R2 pattern)
    float4 lo[8], hi[8];
#pragma unroll
    for (int ks = 0; ks < 8; ++ks) {
      lo[ks] = *(const float4*)(xr + ks * 32);
      hi[ks] = *(const float4*)(xr + ks * 32 + 16);
    }

    unsigned bb = 0;
    asm volatile("" : "+v"(bb));   // opaque 0: blocks LICM/CSE of B frags into VGPRs

    f32x4 acc[4];
#pragma unroll
    for (int nt = 0; nt < 4; ++nt) acc[nt] = (f32x4){0.f, 0.f, 0.f, 0.f};

#pragma unroll
    for (int ks = 0; ks < 8; ++ks) {
      FragA a;
      a.v[0] = to_bf16(lo[ks].x); a.v[1] = to_bf16(lo[ks].y);
      a.v[2] = to_bf16(lo[ks].z); a.v[3] = to_bf16(lo[ks].w);
      a.v[4] = to_bf16(hi[ks].x); a.v[5] = to_bf16(hi[ks].y);
      a.v[6] = to_bf16(hi[ks].z); a.v[7] = to_bf16(hi[ks].w);
#pragma unroll
      for (int nt = 0; nt < 4; ++nt) {
        bf16x8 bv = *(const bf16x8*)&Bl[bb + (ks * 4 + nt) * 512 + lane * 8];
        acc[nt] = __builtin_amdgcn_mfma_f32_16x16x32_bf16(a.v, bv, acc[nt], 0, 0, 0);
      }
    }

    float* ob = out + ((size_t)mt * 16) * 64 + l15;
#pragma unroll
    for (int r = 0; r < 4; ++r)
#pragma unroll
      for (int nt = 0; nt < 4; ++nt)   // r-then-nt: 4 rows x 64B segments
        ob[(4 * lg + r) * 64 + nt * 16] = acc[nt][r];
  }
}

// ---------------------------------------------------------------------------
extern "C" void kernel_launch(void* const* d_in, const int* in_sizes, int n_in,
                              void* d_out, int out_size, void* d_ws, size_t ws_size,
                              hipStream_t stream) {
  const float* x     = (const float*)d_in[0];
  const float* theta = (const float*)d_in[1];
  const float* phi   = (const float*)d_in[2];
  const float* outph = (const float*)d_in[3];
  float* out = (float*)d_out;

  char* ws = (char*)d_ws;
  bool tbl = ws_size >= (size_t)(832 * 1024);
  float4* t4 = (float4*)ws;                       // 512 KB
  float2* t2 = (float2*)(ws + 512 * 1024);        // 256 KB
  __bf16* Tb2 = (__bf16*)(ws + (tbl ? 768 * 1024 : 0));  // 32 KB frag-ordered T

  if (tbl) {
    olk_params<<<128, 256, 0, stream>>>(theta, phi, t4, t2);
    olk_build<true><<<16, 256, 0, stream>>>(theta, phi, outph, t4, t2, Tb2);
  } else {
    olk_build<false><<<16, 256, 0, stream>>>(theta, phi, outph, nullptr, nullptr, Tb2);
  }
  olk_mm<<<1024, 256, 0, stream>>>(x, Tb2, out);
}